// Round 1
// baseline (15393.071 us; speedup 1.0000x reference)
//
#include <hip/hip_runtime.h>

// Scatter-mean graph propagation, 8 rounds (4 fwd + 4 rev).
// Structure per direction:
//   round 1: edge pass accumulates agg[dst] += x[src] AND cnt[dst] += 1
//   normalize: out = agg / max(cnt,1)
//   rounds 2..4: edge pass agg[dst] += prev_out[src]; normalize with cached cnt
// Accumulation lands directly in the d_out slice for that round.

#define BLOCK 256
#define MAX_BLOCKS 2048

// Edge pass with count accumulation (round 1 of a direction).
__global__ void round_first(const float* __restrict__ x,
                            const int* __restrict__ src,
                            const int* __restrict__ dst,
                            float* __restrict__ agg,
                            float* __restrict__ cnt,
                            int nE4, int nE) {
    int i = blockIdx.x * blockDim.x + threadIdx.x;
    int stride = gridDim.x * blockDim.x;
    const int4* src4 = (const int4*)src;
    const int4* dst4 = (const int4*)dst;
    for (; i < nE4; i += stride) {
        int4 s = src4[i];
        int4 d = dst4[i];
        atomicAdd(&agg[d.x], x[s.x]); atomicAdd(&cnt[d.x], 1.0f);
        atomicAdd(&agg[d.y], x[s.y]); atomicAdd(&cnt[d.y], 1.0f);
        atomicAdd(&agg[d.z], x[s.z]); atomicAdd(&cnt[d.z], 1.0f);
        atomicAdd(&agg[d.w], x[s.w]); atomicAdd(&cnt[d.w], 1.0f);
    }
    // scalar tail (nE not divisible by 4) — handled by block 0
    if (blockIdx.x == 0) {
        for (int e = nE4 * 4 + threadIdx.x; e < nE; e += blockDim.x) {
            int s = src[e], d = dst[e];
            atomicAdd(&agg[d], x[s]);
            atomicAdd(&cnt[d], 1.0f);
        }
    }
}

// Edge pass without count accumulation (rounds 2..4).
__global__ void round_next(const float* __restrict__ x,
                           const int* __restrict__ src,
                           const int* __restrict__ dst,
                           float* __restrict__ agg,
                           int nE4, int nE) {
    int i = blockIdx.x * blockDim.x + threadIdx.x;
    int stride = gridDim.x * blockDim.x;
    const int4* src4 = (const int4*)src;
    const int4* dst4 = (const int4*)dst;
    for (; i < nE4; i += stride) {
        int4 s = src4[i];
        int4 d = dst4[i];
        atomicAdd(&agg[d.x], x[s.x]);
        atomicAdd(&agg[d.y], x[s.y]);
        atomicAdd(&agg[d.z], x[s.z]);
        atomicAdd(&agg[d.w], x[s.w]);
    }
    if (blockIdx.x == 0) {
        for (int e = nE4 * 4 + threadIdx.x; e < nE; e += blockDim.x) {
            int s = src[e], d = dst[e];
            atomicAdd(&agg[d], x[s]);
        }
    }
}

// out[i] /= max(cnt[i], 1)
__global__ void normalize_k(float* __restrict__ out,
                            const float* __restrict__ cnt,
                            int n4, int n) {
    int i = blockIdx.x * blockDim.x + threadIdx.x;
    int stride = gridDim.x * blockDim.x;
    float4* o4 = (float4*)out;
    const float4* c4 = (const float4*)cnt;
    for (; i < n4; i += stride) {
        float4 o = o4[i];
        float4 c = c4[i];
        o.x /= fmaxf(c.x, 1.0f);
        o.y /= fmaxf(c.y, 1.0f);
        o.z /= fmaxf(c.z, 1.0f);
        o.w /= fmaxf(c.w, 1.0f);
        o4[i] = o;
    }
    if (blockIdx.x == 0) {
        for (int e = n4 * 4 + threadIdx.x; e < n; e += blockDim.x) {
            out[e] /= fmaxf(cnt[e], 1.0f);
        }
    }
}

extern "C" void kernel_launch(void* const* d_in, const int* in_sizes, int n_in,
                              void* d_out, int out_size, void* d_ws, size_t ws_size,
                              hipStream_t stream) {
    const float* topic = (const float*)d_in[0];
    const int* ei = (const int*)d_in[1];
    const int* rei = (const int*)d_in[2];
    const int N = in_sizes[0];
    const int E = in_sizes[1] / 2;

    const int* src = ei;
    const int* dst = ei + E;
    const int* rsrc = rei;
    const int* rdst = rei + E;

    float* out = (float*)d_out;          // 8 slices of N floats
    float* cnt_f = (float*)d_ws;         // N floats
    float* cnt_r = cnt_f + N;            // N floats

    // Zero accumulators (atomics need zero-init; harness doesn't re-poison).
    hipMemsetAsync(d_out, 0, (size_t)out_size * sizeof(float), stream);
    hipMemsetAsync(d_ws, 0, (size_t)2 * N * sizeof(float), stream);

    const int nE4 = E / 4;
    const int n4 = N / 4;
    int eb = (nE4 + BLOCK - 1) / BLOCK; if (eb > MAX_BLOCKS) eb = MAX_BLOCKS;
    int nb = (n4 + BLOCK - 1) / BLOCK;  if (nb > MAX_BLOCKS) nb = MAX_BLOCKS;

    // ---- forward direction: slices 0..3 ----
    hipLaunchKernelGGL(round_first, dim3(eb), dim3(BLOCK), 0, stream,
                       topic, src, dst, out, cnt_f, nE4, E);
    hipLaunchKernelGGL(normalize_k, dim3(nb), dim3(BLOCK), 0, stream,
                       out, cnt_f, n4, N);
    for (int r = 1; r < 4; ++r) {
        hipLaunchKernelGGL(round_next, dim3(eb), dim3(BLOCK), 0, stream,
                           out + (size_t)(r - 1) * N, src, dst,
                           out + (size_t)r * N, nE4, E);
        hipLaunchKernelGGL(normalize_k, dim3(nb), dim3(BLOCK), 0, stream,
                           out + (size_t)r * N, cnt_f, n4, N);
    }

    // ---- reverse direction: slices 4..7 ----
    hipLaunchKernelGGL(round_first, dim3(eb), dim3(BLOCK), 0, stream,
                       topic, rsrc, rdst, out + (size_t)4 * N, cnt_r, nE4, E);
    hipLaunchKernelGGL(normalize_k, dim3(nb), dim3(BLOCK), 0, stream,
                       out + (size_t)4 * N, cnt_r, n4, N);
    for (int r = 5; r < 8; ++r) {
        hipLaunchKernelGGL(round_next, dim3(eb), dim3(BLOCK), 0, stream,
                           out + (size_t)(r - 1) * N, rsrc, rdst,
                           out + (size_t)r * N, nE4, E);
        hipLaunchKernelGGL(normalize_k, dim3(nb), dim3(BLOCK), 0, stream,
                           out + (size_t)r * N, cnt_f + (size_t)N, n4, N);
    }
}

// Round 2
// 4095.242 us; speedup vs baseline: 3.7588x; 3.7588x over previous
//
#include <hip/hip_runtime.h>

// Scatter-mean graph propagation, 8 rounds (4 fwd + 4 rev).
//
// FAST PATH (no global atomics): per direction,
//   1) partition edges into NB buckets by dst>>8 (histogram -> scan -> scatter),
//      packing each edge as (src<<8)|(dst&255) in one uint32 (128 MB/round stream)
//   2) each round: one block per bucket, LDS fp32 accumulation (ds_add_f32),
//      fused normalize, direct write to the round's output slice.
//      Counts computed once per direction in round 1's LDS pass.
// Rationale: device-scope fp32 atomics execute memory-side on MI355X
// (per-XCD L2s not coherent) -> ~21G atomics/s cap; round-1 profile showed
// WRITE_SIZE = 64M x 32B = 2GB per edge pass. LDS atomics avoid all of it.
//
// FALLBACK (ws too small / shapes unexpected): proven global-atomic version.

#define TPB 256
#define NBLK_PART 1024
#define MAXNB 4096   // max buckets supported by the 16KB LDS arrays

// ---------------- fast path ----------------

__global__ void p1_count(const int* __restrict__ dst, unsigned* __restrict__ blkcnt,
                         int E, int C, int NB) {
    __shared__ unsigned h[MAXNB];
    for (int i = threadIdx.x; i < NB; i += TPB) h[i] = 0u;
    __syncthreads();
    int beg = blockIdx.x * C;
    int end = min(beg + C, E);
    for (int e = beg + threadIdx.x; e < end; e += TPB) {
        unsigned b = ((unsigned)dst[e]) >> 8;
        atomicAdd(&h[b], 1u);
    }
    __syncthreads();
    unsigned* out = blkcnt + (size_t)blockIdx.x * NB;
    for (int i = threadIdx.x; i < NB; i += TPB) out[i] = h[i];
}

__global__ void s1_colsum(const unsigned* __restrict__ blkcnt, unsigned* __restrict__ totals,
                          int NB, int nblk) {
    int b = blockIdx.x * blockDim.x + threadIdx.x;
    if (b >= NB) return;
    unsigned s = 0;
    for (int k = 0; k < nblk; ++k) s += blkcnt[(size_t)k * NB + b];
    totals[b] = s;
}

// single block of 1024 threads scans up to 4096 bucket totals -> exclusive base
__global__ void s2_scan(const unsigned* __restrict__ totals, unsigned* __restrict__ base, int NB) {
    __shared__ unsigned t[1024];
    int tid = threadIdx.x;
    int i0 = tid * 4;
    unsigned v[4], s = 0;
    for (int j = 0; j < 4; ++j) {
        int i = i0 + j;
        v[j] = (i < NB) ? totals[i] : 0u;
        s += v[j];
    }
    t[tid] = s;
    __syncthreads();
    for (int off = 1; off < 1024; off <<= 1) {
        unsigned w = 0;
        if (tid >= off) w = t[tid - off];
        __syncthreads();
        if (tid >= off) t[tid] += w;
        __syncthreads();
    }
    unsigned ex = t[tid] - s;   // exclusive prefix of this thread's 4-chunk
    for (int j = 0; j < 4; ++j) {
        int i = i0 + j;
        if (i <= NB) base[i] = ex;  // base[NB] = grand total (== E)
        ex += v[j];
    }
}

__global__ void s3_start(const unsigned* __restrict__ blkcnt, const unsigned* __restrict__ base,
                         unsigned* __restrict__ start, int NB, int nblk) {
    int b = blockIdx.x * blockDim.x + threadIdx.x;
    if (b >= NB) return;
    unsigned run = base[b];
    for (int k = 0; k < nblk; ++k) {
        size_t idx = (size_t)k * NB + b;
        start[idx] = run;
        run += blkcnt[idx];
    }
}

__global__ void p2_scatter(const int* __restrict__ src, const int* __restrict__ dst,
                           const unsigned* __restrict__ start, unsigned* __restrict__ packed,
                           int E, int C, int NB) {
    __shared__ unsigned cur[MAXNB];
    const unsigned* st = start + (size_t)blockIdx.x * NB;
    for (int i = threadIdx.x; i < NB; i += TPB) cur[i] = st[i];
    __syncthreads();
    int beg = blockIdx.x * C;
    int end = min(beg + C, E);
    for (int e = beg + threadIdx.x; e < end; e += TPB) {
        unsigned s = (unsigned)src[e];
        unsigned d = (unsigned)dst[e];
        unsigned b = d >> 8;
        unsigned pos = atomicAdd(&cur[b], 1u);
        packed[pos] = (s << 8) | (d & 255u);
    }
}

// one block per bucket; LDS accumulate; fused normalize; FIRST also builds counts
template <bool FIRST>
__global__ void e_pass(const float* __restrict__ x, const unsigned* __restrict__ packed,
                       const unsigned* __restrict__ boff, float* __restrict__ cnt,
                       float* __restrict__ outslice, int N) {
    __shared__ float acc[256];
    __shared__ unsigned c[256];
    int tid = threadIdx.x;
    acc[tid] = 0.0f;
    if (FIRST) c[tid] = 0u;
    __syncthreads();
    int b = blockIdx.x;
    int beg = (int)boff[b], end = (int)boff[b + 1];
    for (int e = beg + tid; e < end; e += TPB) {
        unsigned p = packed[e];
        unsigned s = p >> 8;
        unsigned d = p & 255u;
        atomicAdd(&acc[d], x[s]);
        if (FIRST) atomicAdd(&c[d], 1u);
    }
    __syncthreads();
    int node = (b << 8) + tid;
    if (node < N) {
        float cn;
        if (FIRST) { cn = (float)c[tid]; cnt[node] = cn; }
        else cn = cnt[node];
        outslice[node] = acc[tid] / fmaxf(cn, 1.0f);
    }
}

// ---------------- fallback (proven atomic path) ----------------

#define MAX_BLOCKS 2048

__global__ void round_first(const float* __restrict__ x,
                            const int* __restrict__ src,
                            const int* __restrict__ dst,
                            float* __restrict__ agg,
                            float* __restrict__ cnt,
                            int nE4, int nE) {
    int i = blockIdx.x * blockDim.x + threadIdx.x;
    int stride = gridDim.x * blockDim.x;
    const int4* src4 = (const int4*)src;
    const int4* dst4 = (const int4*)dst;
    for (; i < nE4; i += stride) {
        int4 s = src4[i];
        int4 d = dst4[i];
        atomicAdd(&agg[d.x], x[s.x]); atomicAdd(&cnt[d.x], 1.0f);
        atomicAdd(&agg[d.y], x[s.y]); atomicAdd(&cnt[d.y], 1.0f);
        atomicAdd(&agg[d.z], x[s.z]); atomicAdd(&cnt[d.z], 1.0f);
        atomicAdd(&agg[d.w], x[s.w]); atomicAdd(&cnt[d.w], 1.0f);
    }
    if (blockIdx.x == 0) {
        for (int e = nE4 * 4 + threadIdx.x; e < nE; e += blockDim.x) {
            int s = src[e], d = dst[e];
            atomicAdd(&agg[d], x[s]);
            atomicAdd(&cnt[d], 1.0f);
        }
    }
}

__global__ void round_next(const float* __restrict__ x,
                           const int* __restrict__ src,
                           const int* __restrict__ dst,
                           float* __restrict__ agg,
                           int nE4, int nE) {
    int i = blockIdx.x * blockDim.x + threadIdx.x;
    int stride = gridDim.x * blockDim.x;
    const int4* src4 = (const int4*)src;
    const int4* dst4 = (const int4*)dst;
    for (; i < nE4; i += stride) {
        int4 s = src4[i];
        int4 d = dst4[i];
        atomicAdd(&agg[d.x], x[s.x]);
        atomicAdd(&agg[d.y], x[s.y]);
        atomicAdd(&agg[d.z], x[s.z]);
        atomicAdd(&agg[d.w], x[s.w]);
    }
    if (blockIdx.x == 0) {
        for (int e = nE4 * 4 + threadIdx.x; e < nE; e += blockDim.x) {
            int s = src[e], d = dst[e];
            atomicAdd(&agg[d], x[s]);
        }
    }
}

__global__ void normalize_k(float* __restrict__ out,
                            const float* __restrict__ cnt,
                            int n4, int n) {
    int i = blockIdx.x * blockDim.x + threadIdx.x;
    int stride = gridDim.x * blockDim.x;
    float4* o4 = (float4*)out;
    const float4* c4 = (const float4*)cnt;
    for (; i < n4; i += stride) {
        float4 o = o4[i];
        float4 c = c4[i];
        o.x /= fmaxf(c.x, 1.0f);
        o.y /= fmaxf(c.y, 1.0f);
        o.z /= fmaxf(c.z, 1.0f);
        o.w /= fmaxf(c.w, 1.0f);
        o4[i] = o;
    }
    if (blockIdx.x == 0) {
        for (int e = n4 * 4 + threadIdx.x; e < n; e += blockDim.x) {
            out[e] /= fmaxf(cnt[e], 1.0f);
        }
    }
}

// ---------------- launch ----------------

extern "C" void kernel_launch(void* const* d_in, const int* in_sizes, int n_in,
                              void* d_out, int out_size, void* d_ws, size_t ws_size,
                              hipStream_t stream) {
    const float* topic = (const float*)d_in[0];
    const int* ei  = (const int*)d_in[1];
    const int* rei = (const int*)d_in[2];
    const int N = in_sizes[0];
    const int E = in_sizes[1] / 2;

    float* out = (float*)d_out;   // 8 slices of N floats

    const int NB = (N + 255) >> 8;
    const int C  = (E + NBLK_PART - 1) / NBLK_PART;

    // workspace layout (256B-aligned slabs)
    size_t off = 0;
    auto alloc = [&](size_t bytes) { size_t o = off; off += (bytes + 255) & ~(size_t)255; return o; };
    size_t o_packed = alloc((size_t)E * 4);
    size_t o_cnt    = alloc((size_t)N * 4);
    size_t o_blkcnt = alloc((size_t)NBLK_PART * NB * 4);
    size_t o_start  = alloc((size_t)NBLK_PART * NB * 4);
    size_t o_totals = alloc((size_t)NB * 4);
    size_t o_base   = alloc((size_t)(NB + 1) * 4);
    bool fast = (off <= ws_size) && (NB >= 2) && (NB <= 4095) && (N <= (1 << 24));

    if (fast) {
        char* ws = (char*)d_ws;
        unsigned* packed = (unsigned*)(ws + o_packed);
        float*    cnt    = (float*)   (ws + o_cnt);
        unsigned* blkcnt = (unsigned*)(ws + o_blkcnt);
        unsigned* start  = (unsigned*)(ws + o_start);
        unsigned* totals = (unsigned*)(ws + o_totals);
        unsigned* base   = (unsigned*)(ws + o_base);

        const int sgrid = (NB + 255) / 256;

        for (int dir = 0; dir < 2; ++dir) {
            const int* src = (dir == 0) ? ei : rei;
            const int* dst = src + E;
            float* oslab = out + (size_t)dir * 4 * N;

            p1_count<<<NBLK_PART, TPB, 0, stream>>>(dst, blkcnt, E, C, NB);
            s1_colsum<<<sgrid, 256, 0, stream>>>(blkcnt, totals, NB, NBLK_PART);
            s2_scan<<<1, 1024, 0, stream>>>(totals, base, NB);
            s3_start<<<sgrid, 256, 0, stream>>>(blkcnt, base, start, NB, NBLK_PART);
            p2_scatter<<<NBLK_PART, TPB, 0, stream>>>(src, dst, start, packed, E, C, NB);

            e_pass<true><<<NB, 256, 0, stream>>>(topic, packed, base, cnt, oslab, N);
            for (int r = 1; r < 4; ++r) {
                e_pass<false><<<NB, 256, 0, stream>>>(oslab + (size_t)(r - 1) * N, packed,
                                                      base, cnt, oslab + (size_t)r * N, N);
            }
        }
        return;
    }

    // -------- fallback: global-atomic version --------
    const int* src = ei;
    const int* dst = ei + E;
    const int* rsrc = rei;
    const int* rdst = rei + E;

    float* cnt_f = (float*)d_ws;
    float* cnt_r = cnt_f + N;

    hipMemsetAsync(d_out, 0, (size_t)out_size * sizeof(float), stream);
    hipMemsetAsync(d_ws, 0, (size_t)2 * N * sizeof(float), stream);

    const int nE4 = E / 4;
    const int n4 = N / 4;
    int eb = (nE4 + TPB - 1) / TPB; if (eb > MAX_BLOCKS) eb = MAX_BLOCKS;
    int nb = (n4 + TPB - 1) / TPB;  if (nb > MAX_BLOCKS) nb = MAX_BLOCKS;

    round_first<<<eb, TPB, 0, stream>>>(topic, src, dst, out, cnt_f, nE4, E);
    normalize_k<<<nb, TPB, 0, stream>>>(out, cnt_f, n4, N);
    for (int r = 1; r < 4; ++r) {
        round_next<<<eb, TPB, 0, stream>>>(out + (size_t)(r - 1) * N, src, dst,
                                           out + (size_t)r * N, nE4, E);
        normalize_k<<<nb, TPB, 0, stream>>>(out + (size_t)r * N, cnt_f, n4, N);
    }
    round_first<<<eb, TPB, 0, stream>>>(topic, rsrc, rdst, out + (size_t)4 * N, cnt_r, nE4, E);
    normalize_k<<<nb, TPB, 0, stream>>>(out + (size_t)4 * N, cnt_r, n4, N);
    for (int r = 5; r < 8; ++r) {
        round_next<<<eb, TPB, 0, stream>>>(out + (size_t)(r - 1) * N, rsrc, rdst,
                                           out + (size_t)r * N, nE4, E);
        normalize_k<<<nb, TPB, 0, stream>>>(out + (size_t)r * N, cnt_r, n4, N);
    }
}

// Round 3
// 3450.331 us; speedup vs baseline: 4.4613x; 1.1869x over previous
//
#include <hip/hip_runtime.h>

// Scatter-mean graph propagation, 8 rounds (4 fwd + 4 rev).
//
// FAST PATH (no global atomics): per direction,
//   1) partition edges into NB=ceil(N/4096) buckets by dst>>12
//      (histogram -> scan -> scatter), packing each edge as
//      (src<<12)|(dst&4095) in one uint32 (needs N <= 2^20).
//   2) each round: one block (1024 thr) per bucket, LDS fp32 accumulation
//      (ds_add_f32 into acc[4096]), fused normalize, direct write to the
//      round's output slice. Counts computed once per direction (round 1).
// Bucket size 4096 chosen so the scatter's active write-line footprint
// (245 buckets x 64B x ~128 blocks/XCD ~= 2MB) fits per-XCD L2 -> append
// streams assemble into full cache lines (round-2 profile showed 7.5x write
// amplification with 256-node buckets / 3907 streams).
//
// FALLBACK (ws too small / shapes unexpected): proven global-atomic version.

#define TPB 256
#define TPB_E 1024
#define NBLK_PART 1024
#define NBMAX 256      // max buckets (N <= 2^20 -> NB <= 256)
#define BSH 12         // bucket shift
#define BSZ 4096       // nodes per bucket
#define BMASK 4095u

// ---------------- fast path ----------------

__global__ void p1_count(const int* __restrict__ dst, unsigned* __restrict__ blkcnt,
                         int E, int C, int NB) {
    __shared__ unsigned h[NBMAX];
    for (int i = threadIdx.x; i < NB; i += TPB) h[i] = 0u;
    __syncthreads();
    int beg = blockIdx.x * C;
    int end = min(beg + C, E);
    for (int e = beg + threadIdx.x; e < end; e += TPB) {
        unsigned b = ((unsigned)dst[e]) >> BSH;
        atomicAdd(&h[b], 1u);
    }
    __syncthreads();
    unsigned* out = blkcnt + (size_t)blockIdx.x * NB;
    for (int i = threadIdx.x; i < NB; i += TPB) out[i] = h[i];
}

// one block, 256 threads: column-sum over NBLK_PART partition blocks
__global__ void s1_colsum(const unsigned* __restrict__ blkcnt, unsigned* __restrict__ totals,
                          int NB, int nblk) {
    int b = threadIdx.x;
    if (b >= NB) return;
    unsigned s = 0;
    for (int k = 0; k < nblk; ++k) s += blkcnt[(size_t)k * NB + b];
    totals[b] = s;
}

// one block, 256 threads: exclusive scan of <=256 bucket totals
__global__ void s2_scan(const unsigned* __restrict__ totals, unsigned* __restrict__ base, int NB) {
    __shared__ unsigned t[256];
    int tid = threadIdx.x;
    unsigned v = (tid < NB) ? totals[tid] : 0u;
    t[tid] = v;
    __syncthreads();
    for (int off = 1; off < 256; off <<= 1) {
        unsigned w = 0;
        if (tid >= off) w = t[tid - off];
        __syncthreads();
        if (tid >= off) t[tid] += w;
        __syncthreads();
    }
    unsigned incl = t[tid];
    if (tid < NB) base[tid] = incl - v;        // exclusive prefix
    if (tid == NB - 1) base[NB] = incl;        // grand total == E
}

// one block, 256 threads: per (partition-block, bucket) start positions
__global__ void s3_start(const unsigned* __restrict__ blkcnt, const unsigned* __restrict__ base,
                         unsigned* __restrict__ start, int NB, int nblk) {
    int b = threadIdx.x;
    if (b >= NB) return;
    unsigned run = base[b];
    for (int k = 0; k < nblk; ++k) {
        size_t idx = (size_t)k * NB + b;
        start[idx] = run;
        run += blkcnt[idx];
    }
}

__global__ void p2_scatter(const int* __restrict__ src, const int* __restrict__ dst,
                           const unsigned* __restrict__ start, unsigned* __restrict__ packed,
                           int E, int C, int NB) {
    __shared__ unsigned cur[NBMAX];
    const unsigned* st = start + (size_t)blockIdx.x * NB;
    for (int i = threadIdx.x; i < NB; i += TPB) cur[i] = st[i];
    __syncthreads();
    int beg = blockIdx.x * C;
    int end = min(beg + C, E);
    for (int e = beg + threadIdx.x; e < end; e += TPB) {
        unsigned s = (unsigned)src[e];
        unsigned d = (unsigned)dst[e];
        unsigned b = d >> BSH;
        unsigned pos = atomicAdd(&cur[b], 1u);
        packed[pos] = (s << BSH) | (d & BMASK);
    }
}

// one block per bucket; LDS accumulate; fused normalize; FIRST also builds counts
template <bool FIRST>
__global__ __launch_bounds__(TPB_E)
void e_pass(const float* __restrict__ x, const unsigned* __restrict__ packed,
            const unsigned* __restrict__ boff, float* __restrict__ cnt,
            float* __restrict__ outslice, int N) {
    __shared__ float acc[BSZ];
    __shared__ unsigned c[BSZ];
    int tid = threadIdx.x;
    for (int i = tid; i < BSZ; i += TPB_E) {
        acc[i] = 0.0f;
        if (FIRST) c[i] = 0u;
    }
    __syncthreads();
    int b = blockIdx.x;
    int beg = (int)boff[b], end = (int)boff[b + 1];
    for (int e = beg + tid; e < end; e += TPB_E) {
        unsigned p = packed[e];
        atomicAdd(&acc[p & BMASK], x[p >> BSH]);
        if (FIRST) atomicAdd(&c[p & BMASK], 1u);
    }
    __syncthreads();
    int nbase = b << BSH;
    for (int i = tid; i < BSZ; i += TPB_E) {
        int node = nbase + i;
        if (node < N) {
            float cn;
            if (FIRST) { cn = (float)c[i]; cnt[node] = cn; }
            else cn = cnt[node];
            outslice[node] = acc[i] / fmaxf(cn, 1.0f);
        }
    }
}

// ---------------- fallback (proven atomic path) ----------------

#define MAX_BLOCKS 2048

__global__ void round_first(const float* __restrict__ x,
                            const int* __restrict__ src,
                            const int* __restrict__ dst,
                            float* __restrict__ agg,
                            float* __restrict__ cnt,
                            int nE4, int nE) {
    int i = blockIdx.x * blockDim.x + threadIdx.x;
    int stride = gridDim.x * blockDim.x;
    const int4* src4 = (const int4*)src;
    const int4* dst4 = (const int4*)dst;
    for (; i < nE4; i += stride) {
        int4 s = src4[i];
        int4 d = dst4[i];
        atomicAdd(&agg[d.x], x[s.x]); atomicAdd(&cnt[d.x], 1.0f);
        atomicAdd(&agg[d.y], x[s.y]); atomicAdd(&cnt[d.y], 1.0f);
        atomicAdd(&agg[d.z], x[s.z]); atomicAdd(&cnt[d.z], 1.0f);
        atomicAdd(&agg[d.w], x[s.w]); atomicAdd(&cnt[d.w], 1.0f);
    }
    if (blockIdx.x == 0) {
        for (int e = nE4 * 4 + threadIdx.x; e < nE; e += blockDim.x) {
            int s = src[e], d = dst[e];
            atomicAdd(&agg[d], x[s]);
            atomicAdd(&cnt[d], 1.0f);
        }
    }
}

__global__ void round_next(const float* __restrict__ x,
                           const int* __restrict__ src,
                           const int* __restrict__ dst,
                           float* __restrict__ agg,
                           int nE4, int nE) {
    int i = blockIdx.x * blockDim.x + threadIdx.x;
    int stride = gridDim.x * blockDim.x;
    const int4* src4 = (const int4*)src;
    const int4* dst4 = (const int4*)dst;
    for (; i < nE4; i += stride) {
        int4 s = src4[i];
        int4 d = dst4[i];
        atomicAdd(&agg[d.x], x[s.x]);
        atomicAdd(&agg[d.y], x[s.y]);
        atomicAdd(&agg[d.z], x[s.z]);
        atomicAdd(&agg[d.w], x[s.w]);
    }
    if (blockIdx.x == 0) {
        for (int e = nE4 * 4 + threadIdx.x; e < nE; e += blockDim.x) {
            int s = src[e], d = dst[e];
            atomicAdd(&agg[d], x[s]);
        }
    }
}

__global__ void normalize_k(float* __restrict__ out,
                            const float* __restrict__ cnt,
                            int n4, int n) {
    int i = blockIdx.x * blockDim.x + threadIdx.x;
    int stride = gridDim.x * blockDim.x;
    float4* o4 = (float4*)out;
    const float4* c4 = (const float4*)cnt;
    for (; i < n4; i += stride) {
        float4 o = o4[i];
        float4 c = c4[i];
        o.x /= fmaxf(c.x, 1.0f);
        o.y /= fmaxf(c.y, 1.0f);
        o.z /= fmaxf(c.z, 1.0f);
        o.w /= fmaxf(c.w, 1.0f);
        o4[i] = o;
    }
    if (blockIdx.x == 0) {
        for (int e = n4 * 4 + threadIdx.x; e < n; e += blockDim.x) {
            out[e] /= fmaxf(cnt[e], 1.0f);
        }
    }
}

// ---------------- launch ----------------

extern "C" void kernel_launch(void* const* d_in, const int* in_sizes, int n_in,
                              void* d_out, int out_size, void* d_ws, size_t ws_size,
                              hipStream_t stream) {
    const float* topic = (const float*)d_in[0];
    const int* ei  = (const int*)d_in[1];
    const int* rei = (const int*)d_in[2];
    const int N = in_sizes[0];
    const int E = in_sizes[1] / 2;

    float* out = (float*)d_out;   // 8 slices of N floats

    const int NB = (N + BSZ - 1) >> BSH;
    const int C  = (E + NBLK_PART - 1) / NBLK_PART;

    // workspace layout (256B-aligned slabs)
    size_t off = 0;
    auto alloc = [&](size_t bytes) { size_t o = off; off += (bytes + 255) & ~(size_t)255; return o; };
    size_t o_packed = alloc((size_t)E * 4);
    size_t o_cnt    = alloc((size_t)N * 4);
    size_t o_blkcnt = alloc((size_t)NBLK_PART * NB * 4);
    size_t o_start  = alloc((size_t)NBLK_PART * NB * 4);
    size_t o_totals = alloc((size_t)NBMAX * 4);
    size_t o_base   = alloc((size_t)(NBMAX + 1) * 4);
    bool fast = (off <= ws_size) && (NB >= 2) && (NB <= NBMAX) && (N <= (1 << 20));

    if (fast) {
        char* ws = (char*)d_ws;
        unsigned* packed = (unsigned*)(ws + o_packed);
        float*    cnt    = (float*)   (ws + o_cnt);
        unsigned* blkcnt = (unsigned*)(ws + o_blkcnt);
        unsigned* start  = (unsigned*)(ws + o_start);
        unsigned* totals = (unsigned*)(ws + o_totals);
        unsigned* base   = (unsigned*)(ws + o_base);

        for (int dir = 0; dir < 2; ++dir) {
            const int* src = (dir == 0) ? ei : rei;
            const int* dst = src + E;
            float* oslab = out + (size_t)dir * 4 * N;

            p1_count<<<NBLK_PART, TPB, 0, stream>>>(dst, blkcnt, E, C, NB);
            s1_colsum<<<1, 256, 0, stream>>>(blkcnt, totals, NB, NBLK_PART);
            s2_scan<<<1, 256, 0, stream>>>(totals, base, NB);
            s3_start<<<1, 256, 0, stream>>>(blkcnt, base, start, NB, NBLK_PART);
            p2_scatter<<<NBLK_PART, TPB, 0, stream>>>(src, dst, start, packed, E, C, NB);

            e_pass<true><<<NB, TPB_E, 0, stream>>>(topic, packed, base, cnt, oslab, N);
            for (int r = 1; r < 4; ++r) {
                e_pass<false><<<NB, TPB_E, 0, stream>>>(oslab + (size_t)(r - 1) * N, packed,
                                                        base, cnt, oslab + (size_t)r * N, N);
            }
        }
        return;
    }

    // -------- fallback: global-atomic version --------
    const int* src = ei;
    const int* dst = ei + E;
    const int* rsrc = rei;
    const int* rdst = rei + E;

    float* cnt_f = (float*)d_ws;
    float* cnt_r = cnt_f + N;

    hipMemsetAsync(d_out, 0, (size_t)out_size * sizeof(float), stream);
    hipMemsetAsync(d_ws, 0, (size_t)2 * N * sizeof(float), stream);

    const int nE4 = E / 4;
    const int n4 = N / 4;
    int eb = (nE4 + TPB - 1) / TPB; if (eb > MAX_BLOCKS) eb = MAX_BLOCKS;
    int nb = (n4 + TPB - 1) / TPB;  if (nb > MAX_BLOCKS) nb = MAX_BLOCKS;

    round_first<<<eb, TPB, 0, stream>>>(topic, src, dst, out, cnt_f, nE4, E);
    normalize_k<<<nb, TPB, 0, stream>>>(out, cnt_f, n4, N);
    for (int r = 1; r < 4; ++r) {
        round_next<<<eb, TPB, 0, stream>>>(out + (size_t)(r - 1) * N, src, dst,
                                           out + (size_t)r * N, nE4, E);
        normalize_k<<<nb, TPB, 0, stream>>>(out + (size_t)r * N, cnt_f, n4, N);
    }
    round_first<<<eb, TPB, 0, stream>>>(topic, rsrc, rdst, out + (size_t)4 * N, cnt_r, nE4, E);
    normalize_k<<<nb, TPB, 0, stream>>>(out + (size_t)4 * N, cnt_r, n4, N);
    for (int r = 5; r < 8; ++r) {
        round_next<<<eb, TPB, 0, stream>>>(out + (size_t)(r - 1) * N, rsrc, rdst,
                                           out + (size_t)r * N, nE4, E);
        normalize_k<<<nb, TPB, 0, stream>>>(out + (size_t)r * N, cnt_r, n4, N);
    }
}

// Round 5
// 1722.203 us; speedup vs baseline: 8.9380x; 2.0034x over previous
//
#include <hip/hip_runtime.h>

// Scatter-mean graph propagation, 8 rounds (4 fwd + 4 rev).
//
// FAST PATH (no global atomics): per direction,
//   1) partition edges into NB=ceil(N/2048) buckets by dst>>11
//      (histogram -> scan -> staged scatter), packing each edge as
//      (src<<11)|(dst&2047) in one uint32 (needs N <= 2^20).
//      The scatter stages edges in LDS (per-bucket slots, cap 32) and each
//      wave flushes whole bucket runs as line-contiguous bursts -> coalesced
//      writes (round-3 profile: unstaged scatter had 5.8x write amplification,
//      737MB writes for 128MB payload). nontemporal loads on src/dst protect
//      the partial write lines in per-XCD L2.
//   2) each round: one block (1024 thr) per bucket, LDS fp32 accumulation
//      into acc[2048], fused normalize, direct write to the round's output
//      slice. Counts computed once per direction (round 1). NB=489 blocks
//      ~= 2/CU -> ~32 waves/CU (was 245 = 1/CU at BSZ=4096).
//
// NOTE: __builtin_nontemporal_load requires a clang ext_vector type, not
// HIP's uint4 class -> use uint32x4 below (round-4 compile failure).
//
// FALLBACK (ws too small / shapes unexpected): proven global-atomic version.

typedef unsigned uint32x4 __attribute__((ext_vector_type(4)));

#define TPB_E 1024
#define NPART 512
#define TPB_P 512
#define BATCH 8192
#define CAP 32
#define NBMAX 512      // max buckets (N <= 2^20 -> NB <= 512)
#define BSH 11         // bucket shift
#define BSZ 2048       // nodes per bucket
#define BMASK 2047u

// ---------------- fast path ----------------

__global__ __launch_bounds__(TPB_P)
void p1_count(const int* __restrict__ dst, unsigned* __restrict__ blkcnt,
              int E, int chunk, int NB) {
    __shared__ unsigned h[NBMAX];
    for (int i = threadIdx.x; i < NB; i += TPB_P) h[i] = 0u;
    __syncthreads();
    int beg = blockIdx.x * chunk;
    int end = min(beg + chunk, E);
    int len = end - beg; if (len < 0) len = 0;
    const uint32x4* d4 = (const uint32x4*)(dst + beg);   // beg multiple of 16 -> aligned
    int n4 = len >> 2;
    for (int i = threadIdx.x; i < n4; i += TPB_P) {
        uint32x4 d = __builtin_nontemporal_load(&d4[i]);
        atomicAdd(&h[d.x >> BSH], 1u);
        atomicAdd(&h[d.y >> BSH], 1u);
        atomicAdd(&h[d.z >> BSH], 1u);
        atomicAdd(&h[d.w >> BSH], 1u);
    }
    __syncthreads();
    unsigned* o = blkcnt + (size_t)blockIdx.x * NB;
    for (int i = threadIdx.x; i < NB; i += TPB_P) o[i] = h[i];
}

// block per bucket: total over partition blocks
__global__ __launch_bounds__(TPB_P)
void s1_totals(const unsigned* __restrict__ blkcnt, unsigned* __restrict__ totals,
               int NB, int nblk) {
    __shared__ unsigned red[TPB_P];
    int b = blockIdx.x;
    unsigned s = 0;
    for (int k = threadIdx.x; k < nblk; k += TPB_P) s += blkcnt[(size_t)k * NB + b];
    red[threadIdx.x] = s;
    __syncthreads();
    for (int off = TPB_P / 2; off > 0; off >>= 1) {
        if (threadIdx.x < off) red[threadIdx.x] += red[threadIdx.x + off];
        __syncthreads();
    }
    if (threadIdx.x == 0) totals[b] = red[0];
}

// one block: exclusive scan of <=512 bucket totals; base[NB] = E
__global__ __launch_bounds__(TPB_P)
void s2_scan(const unsigned* __restrict__ totals, unsigned* __restrict__ base, int NB) {
    __shared__ unsigned t[TPB_P];
    int tid = threadIdx.x;
    unsigned v = (tid < NB) ? totals[tid] : 0u;
    t[tid] = v;
    __syncthreads();
    for (int off = 1; off < TPB_P; off <<= 1) {
        unsigned w = (tid >= off) ? t[tid - off] : 0u;
        __syncthreads();
        t[tid] += w;
        __syncthreads();
    }
    if (tid < NB) base[tid] = t[tid] - v;
    if (tid == NB - 1) base[NB] = t[tid];
}

// block per bucket: exclusive scan over partition blocks -> start positions
__global__ __launch_bounds__(TPB_P)
void s3_start(const unsigned* __restrict__ blkcnt, const unsigned* __restrict__ base,
              unsigned* __restrict__ start, int NB, int nblk) {
    __shared__ unsigned t[TPB_P];
    int b = blockIdx.x;
    int tid = threadIdx.x;
    unsigned v = (tid < nblk) ? blkcnt[(size_t)tid * NB + b] : 0u;
    t[tid] = v;
    __syncthreads();
    for (int off = 1; off < TPB_P; off <<= 1) {
        unsigned w = (tid >= off) ? t[tid - off] : 0u;
        __syncthreads();
        t[tid] += w;
        __syncthreads();
    }
    if (tid < nblk) start[(size_t)tid * NB + b] = base[b] + t[tid] - v;
}

// LDS-staged scatter with wave-cooperative coalesced flush
__global__ __launch_bounds__(TPB_P)
void p2_scatter(const int* __restrict__ src, const int* __restrict__ dst,
                const unsigned* __restrict__ start, unsigned* __restrict__ packed,
                int E, int chunk, int NB) {
    __shared__ unsigned stg[NBMAX * CAP];   // 64 KB staging
    __shared__ unsigned h[NBMAX];           // per-batch bucket counts
    __shared__ unsigned gcur[NBMAX];        // block's running global cursor
    int tid = threadIdx.x;
    int bid = blockIdx.x;
    for (int i = tid; i < NB; i += TPB_P) gcur[i] = start[(size_t)bid * NB + i];
    int beg = bid * chunk;
    int end = min(beg + chunk, E);
    int wid = tid >> 6, lane = tid & 63;
    for (int bb = beg; bb < end; bb += BATCH) {
        int bend = min(bb + BATCH, end);
        int n4 = (bend - bb) >> 2;          // batch size multiple of 16
        for (int i = tid; i < NB; i += TPB_P) h[i] = 0u;
        __syncthreads();
        const uint32x4* s4 = (const uint32x4*)(src + bb);
        const uint32x4* d4 = (const uint32x4*)(dst + bb);
        for (int i = tid; i < n4; i += TPB_P) {
            uint32x4 s = __builtin_nontemporal_load(&s4[i]);
            uint32x4 d = __builtin_nontemporal_load(&d4[i]);
            unsigned sv[4] = {s.x, s.y, s.z, s.w};
            unsigned dv[4] = {d.x, d.y, d.z, d.w};
            #pragma unroll
            for (int k = 0; k < 4; ++k) {
                unsigned b = dv[k] >> BSH;
                unsigned val = (sv[k] << BSH) | (dv[k] & BMASK);
                unsigned pos = atomicAdd(&h[b], 1u);
                if (pos < CAP) stg[(b << 5) + ((pos + b) & 31u)] = val;  // bank-rotated
                else packed[gcur[b] + pos] = val;   // rare overflow (Poisson tail)
            }
        }
        __syncthreads();
        // flush: wave w owns buckets w, w+NW, ... -> line-contiguous bursts
        for (int b = wid; b < NB; b += TPB_P / 64) {
            unsigned cnt = h[b];
            unsigned n = cnt < CAP ? cnt : CAP;
            unsigned g0 = gcur[b];
            for (unsigned i = lane; i < n; i += 64)
                packed[g0 + i] = stg[(b << 5) + ((i + b) & 31u)];
            if (lane == 0) gcur[b] = g0 + cnt;
        }
        __syncthreads();
    }
}

// one block per bucket; LDS accumulate; fused normalize; FIRST also builds counts
template <bool FIRST>
__global__ __launch_bounds__(TPB_E)
void e_pass(const float* __restrict__ x, const unsigned* __restrict__ packed,
            const unsigned* __restrict__ boff, float* __restrict__ cnt,
            float* __restrict__ outslice, int N) {
    __shared__ float acc[BSZ];
    __shared__ unsigned c[FIRST ? BSZ : 1];
    int tid = threadIdx.x;
    for (int i = tid; i < BSZ; i += TPB_E) {
        acc[i] = 0.0f;
        if (FIRST) c[i] = 0u;
    }
    __syncthreads();
    int b = blockIdx.x;
    int beg = (int)boff[b], end = (int)boff[b + 1];
    int a0 = min((beg + 3) & ~3, end);
    for (int e = beg + tid; e < a0; e += TPB_E) {       // unaligned head
        unsigned p = packed[e];
        atomicAdd(&acc[p & BMASK], x[p >> BSH]);
        if (FIRST) atomicAdd(&c[p & BMASK], 1u);
    }
    int i0 = a0 >> 2, i1 = i0 + ((end - a0) >> 2);
    const uint32x4* p4 = (const uint32x4*)packed;
    for (int i = i0 + tid; i < i1; i += TPB_E) {        // vector body
        uint32x4 p = p4[i];
        float x0 = x[p.x >> BSH];
        float x1 = x[p.y >> BSH];
        float x2 = x[p.z >> BSH];
        float x3 = x[p.w >> BSH];
        atomicAdd(&acc[p.x & BMASK], x0);
        atomicAdd(&acc[p.y & BMASK], x1);
        atomicAdd(&acc[p.z & BMASK], x2);
        atomicAdd(&acc[p.w & BMASK], x3);
        if (FIRST) {
            atomicAdd(&c[p.x & BMASK], 1u);
            atomicAdd(&c[p.y & BMASK], 1u);
            atomicAdd(&c[p.z & BMASK], 1u);
            atomicAdd(&c[p.w & BMASK], 1u);
        }
    }
    for (int e = a0 + ((end - a0) & ~3) + tid; e < end; e += TPB_E) {  // tail
        unsigned p = packed[e];
        atomicAdd(&acc[p & BMASK], x[p >> BSH]);
        if (FIRST) atomicAdd(&c[p & BMASK], 1u);
    }
    __syncthreads();
    int nbase = b << BSH;
    for (int i = tid; i < BSZ; i += TPB_E) {
        int node = nbase + i;
        if (node < N) {
            float cn = FIRST ? (float)c[i] : cnt[node];
            if (FIRST) cnt[node] = cn;
            outslice[node] = acc[i] / fmaxf(cn, 1.0f);
        }
    }
}

// ---------------- fallback (proven atomic path) ----------------

#define TPB 256
#define MAX_BLOCKS 2048

__global__ void round_first(const float* __restrict__ x,
                            const int* __restrict__ src,
                            const int* __restrict__ dst,
                            float* __restrict__ agg,
                            float* __restrict__ cnt,
                            int nE4, int nE) {
    int i = blockIdx.x * blockDim.x + threadIdx.x;
    int stride = gridDim.x * blockDim.x;
    const int4* src4 = (const int4*)src;
    const int4* dst4 = (const int4*)dst;
    for (; i < nE4; i += stride) {
        int4 s = src4[i];
        int4 d = dst4[i];
        atomicAdd(&agg[d.x], x[s.x]); atomicAdd(&cnt[d.x], 1.0f);
        atomicAdd(&agg[d.y], x[s.y]); atomicAdd(&cnt[d.y], 1.0f);
        atomicAdd(&agg[d.z], x[s.z]); atomicAdd(&cnt[d.z], 1.0f);
        atomicAdd(&agg[d.w], x[s.w]); atomicAdd(&cnt[d.w], 1.0f);
    }
    if (blockIdx.x == 0) {
        for (int e = nE4 * 4 + threadIdx.x; e < nE; e += blockDim.x) {
            int s = src[e], d = dst[e];
            atomicAdd(&agg[d], x[s]);
            atomicAdd(&cnt[d], 1.0f);
        }
    }
}

__global__ void round_next(const float* __restrict__ x,
                           const int* __restrict__ src,
                           const int* __restrict__ dst,
                           float* __restrict__ agg,
                           int nE4, int nE) {
    int i = blockIdx.x * blockDim.x + threadIdx.x;
    int stride = gridDim.x * blockDim.x;
    const int4* src4 = (const int4*)src;
    const int4* dst4 = (const int4*)dst;
    for (; i < nE4; i += stride) {
        int4 s = src4[i];
        int4 d = dst4[i];
        atomicAdd(&agg[d.x], x[s.x]);
        atomicAdd(&agg[d.y], x[s.y]);
        atomicAdd(&agg[d.z], x[s.z]);
        atomicAdd(&agg[d.w], x[s.w]);
    }
    if (blockIdx.x == 0) {
        for (int e = nE4 * 4 + threadIdx.x; e < nE; e += blockDim.x) {
            int s = src[e], d = dst[e];
            atomicAdd(&agg[d], x[s]);
        }
    }
}

__global__ void normalize_k(float* __restrict__ out,
                            const float* __restrict__ cnt,
                            int n4, int n) {
    int i = blockIdx.x * blockDim.x + threadIdx.x;
    int stride = gridDim.x * blockDim.x;
    float4* o4 = (float4*)out;
    const float4* c4 = (const float4*)cnt;
    for (; i < n4; i += stride) {
        float4 o = o4[i];
        float4 c = c4[i];
        o.x /= fmaxf(c.x, 1.0f);
        o.y /= fmaxf(c.y, 1.0f);
        o.z /= fmaxf(c.z, 1.0f);
        o.w /= fmaxf(c.w, 1.0f);
        o4[i] = o;
    }
    if (blockIdx.x == 0) {
        for (int e = n4 * 4 + threadIdx.x; e < n; e += blockDim.x) {
            out[e] /= fmaxf(cnt[e], 1.0f);
        }
    }
}

// ---------------- launch ----------------

extern "C" void kernel_launch(void* const* d_in, const int* in_sizes, int n_in,
                              void* d_out, int out_size, void* d_ws, size_t ws_size,
                              hipStream_t stream) {
    const float* topic = (const float*)d_in[0];
    const int* ei  = (const int*)d_in[1];
    const int* rei = (const int*)d_in[2];
    const int N = in_sizes[0];
    const int E = in_sizes[1] / 2;

    float* out = (float*)d_out;   // 8 slices of N floats

    const int NB = (N + BSZ - 1) >> BSH;
    const int chunk = ((E + NPART * 16 - 1) / (NPART * 16)) * 16;

    // workspace layout (256B-aligned slabs)
    size_t off = 0;
    auto alloc = [&](size_t bytes) { size_t o = off; off += (bytes + 255) & ~(size_t)255; return o; };
    size_t o_packed = alloc((size_t)E * 4);
    size_t o_cnt    = alloc((size_t)N * 4);
    size_t o_blkcnt = alloc((size_t)NPART * NB * 4);
    size_t o_start  = alloc((size_t)NPART * NB * 4);
    size_t o_totals = alloc((size_t)NBMAX * 4);
    size_t o_base   = alloc((size_t)(NBMAX + 1) * 4);
    bool fast = (off <= ws_size) && (NB >= 2) && (NB <= NBMAX) &&
                (N <= (1 << 20)) && (E % 16 == 0);

    if (fast) {
        char* ws = (char*)d_ws;
        unsigned* packed = (unsigned*)(ws + o_packed);
        float*    cnt    = (float*)   (ws + o_cnt);
        unsigned* blkcnt = (unsigned*)(ws + o_blkcnt);
        unsigned* start  = (unsigned*)(ws + o_start);
        unsigned* totals = (unsigned*)(ws + o_totals);
        unsigned* base   = (unsigned*)(ws + o_base);

        for (int dir = 0; dir < 2; ++dir) {
            const int* src = (dir == 0) ? ei : rei;
            const int* dst = src + E;
            float* oslab = out + (size_t)dir * 4 * N;

            p1_count<<<NPART, TPB_P, 0, stream>>>(dst, blkcnt, E, chunk, NB);
            s1_totals<<<NB, TPB_P, 0, stream>>>(blkcnt, totals, NB, NPART);
            s2_scan<<<1, TPB_P, 0, stream>>>(totals, base, NB);
            s3_start<<<NB, TPB_P, 0, stream>>>(blkcnt, base, start, NB, NPART);
            p2_scatter<<<NPART, TPB_P, 0, stream>>>(src, dst, start, packed, E, chunk, NB);

            e_pass<true><<<NB, TPB_E, 0, stream>>>(topic, packed, base, cnt, oslab, N);
            for (int r = 1; r < 4; ++r) {
                e_pass<false><<<NB, TPB_E, 0, stream>>>(oslab + (size_t)(r - 1) * N, packed,
                                                        base, cnt, oslab + (size_t)r * N, N);
            }
        }
        return;
    }

    // -------- fallback: global-atomic version --------
    const int* src = ei;
    const int* dst = ei + E;
    const int* rsrc = rei;
    const int* rdst = rei + E;

    float* cnt_f = (float*)d_ws;
    float* cnt_r = cnt_f + N;

    (void)hipMemsetAsync(d_out, 0, (size_t)out_size * sizeof(float), stream);
    (void)hipMemsetAsync(d_ws, 0, (size_t)2 * N * sizeof(float), stream);

    const int nE4 = E / 4;
    const int n4 = N / 4;
    int eb = (nE4 + TPB - 1) / TPB; if (eb > MAX_BLOCKS) eb = MAX_BLOCKS;
    int nb = (n4 + TPB - 1) / TPB;  if (nb > MAX_BLOCKS) nb = MAX_BLOCKS;

    round_first<<<eb, TPB, 0, stream>>>(topic, src, dst, out, cnt_f, nE4, E);
    normalize_k<<<nb, TPB, 0, stream>>>(out, cnt_f, n4, N);
    for (int r = 1; r < 4; ++r) {
        round_next<<<eb, TPB, 0, stream>>>(out + (size_t)(r - 1) * N, src, dst,
                                           out + (size_t)r * N, nE4, E);
        normalize_k<<<nb, TPB, 0, stream>>>(out + (size_t)r * N, cnt_f, n4, N);
    }
    round_first<<<eb, TPB, 0, stream>>>(topic, rsrc, rdst, out + (size_t)4 * N, cnt_r, nE4, E);
    normalize_k<<<nb, TPB, 0, stream>>>(out + (size_t)4 * N, cnt_r, n4, N);
    for (int r = 5; r < 8; ++r) {
        round_next<<<eb, TPB, 0, stream>>>(out + (size_t)(r - 1) * N, rsrc, rdst,
                                           out + (size_t)r * N, nE4, E);
        normalize_k<<<nb, TPB, 0, stream>>>(out + (size_t)r * N, cnt_r, n4, N);
    }
}